// Round 10
// baseline (340.552 us; speedup 1.0000x reference)
//
#include <hip/hip_runtime.h>
#include <hip/hip_bf16.h>

// DOMINANT GCN autoencoder on MI355X.
// R10: aggregate+next-GEMM fusion. Aggregate waves idle ~80% on gather vmcnt;
// the per-node 64->64 matvec (next layer's GEMM) runs in those stall cycles:
//   fused1: agg(g1)+b1,relu -> h ; g2 = bf16(dis*(h@W2))      [was agg+gemm]
//   fused2: agg(g2)+b2,relu -> z (fp32 d_out); g3 = bf16(dis*(z@W3))
//   agg3  : plain aggregate -> s3 = bf16(dis*relu(...))        [unchanged]
//   fused4: agg(s3) -> t ; x_hat = t@W4 + b4 (W4 bf16 in LDS)
// 16 launches -> 11; act/t fp32 round-trips eliminated; 2 ping-pong tables.
// Aggregation core = R7/R9 half-wave uint gathers (at the ~3.3 TB/s
// random-gather byte ceiling; R7 MLP / R8 L2-fit attacks were neutral).

// ---------------- CSR build ----------------

__global__ __launch_bounds__(256) void init_k(int* __restrict__ deg, int Npad) {
    int i = blockIdx.x * 256 + threadIdx.x;
    if (i < Npad) deg[i] = 0;
}

__global__ __launch_bounds__(256) void hist_deg(const int* __restrict__ dst,
                                                int* __restrict__ deg, int E) {
    int e = blockIdx.x * 256 + threadIdx.x;
    if (e < E) atomicAdd(&deg[dst[e]], 1);
}

__global__ __launch_bounds__(256) void scan_phase1(const int* __restrict__ deg,
                                                   int* __restrict__ block_sums) {
    int b = blockIdx.x, t = threadIdx.x;
    const int4* p = reinterpret_cast<const int4*>(deg + (size_t)b * 2048);
    int4 a = p[t * 2], c = p[t * 2 + 1];
    int s = a.x + a.y + a.z + a.w + c.x + c.y + c.z + c.w;
#pragma unroll
    for (int off = 32; off; off >>= 1) s += __shfl_down(s, off);
    __shared__ int wsum[4];
    if ((t & 63) == 0) wsum[t >> 6] = s;
    __syncthreads();
    if (t == 0) block_sums[b] = wsum[0] + wsum[1] + wsum[2] + wsum[3];
}

__global__ __launch_bounds__(256) void scan_phase2(const int* __restrict__ block_sums,
                                                   int* __restrict__ block_off,
                                                   int* __restrict__ row_ptr,
                                                   int B, int N) {
    __shared__ int s[256];
    int t = threadIdx.x;
    int v = (t < B) ? block_sums[t] : 0;
    s[t] = v;
    __syncthreads();
#pragma unroll
    for (int off = 1; off < 256; off <<= 1) {
        int u = (t >= off) ? s[t - off] : 0;
        __syncthreads();
        s[t] += u;
        __syncthreads();
    }
    if (t < B) block_off[t] = s[t] - v;
    if (t == 255) row_ptr[N] = s[255];
}

__global__ __launch_bounds__(256) void scan_phase3(const int* __restrict__ deg,
                                                   const int* __restrict__ block_off,
                                                   int* __restrict__ row_ptr,
                                                   float* __restrict__ dis, int N) {
    int b = blockIdx.x, t = threadIdx.x;
    int base = b * 2048 + t * 8;
    const int4* p = reinterpret_cast<const int4*>(deg + base);
    int4 a = p[0], c = p[1];
    int d[8] = {a.x, a.y, a.z, a.w, c.x, c.y, c.z, c.w};
    int pre[8], s = 0;
#pragma unroll
    for (int j = 0; j < 8; ++j) { pre[j] = s; s += d[j]; }
    __shared__ int ls[256];
    ls[t] = s;
    __syncthreads();
#pragma unroll
    for (int off = 1; off < 256; off <<= 1) {
        int u = (t >= off) ? ls[t - off] : 0;
        __syncthreads();
        ls[t] += u;
        __syncthreads();
    }
    int excl = ls[t] - s + block_off[b];
#pragma unroll
    for (int j = 0; j < 8; ++j) {
        int i = base + j;
        if (i < N) {
            row_ptr[i] = excl + pre[j];
            dis[i] = rsqrtf((float)(d[j] + 1));
        }
    }
}

__global__ __launch_bounds__(256) void fill_csr(const int* __restrict__ src,
                                                const int* __restrict__ dst,
                                                const int* __restrict__ row_ptr,
                                                int* __restrict__ deg,
                                                int* __restrict__ csr_src, int E) {
    int e = blockIdx.x * 256 + threadIdx.x;
    if (e < E) {
        int d = dst[e];
        int old = atomicSub(&deg[d], 1);
        csr_src[row_ptr[d] + old - 1] = src[e];
    }
}

// ---------------- helpers ----------------

__device__ __forceinline__ ushort r16(float f) {
    __hip_bfloat16 h = __float2bfloat16(f);   // round-to-nearest-even
    return *reinterpret_cast<ushort*>(&h);
}
__device__ __forceinline__ float bf_lo(unsigned u) {
    return __builtin_bit_cast(float, u << 16);
}
__device__ __forceinline__ float bf_hi(unsigned u) {
    return __builtin_bit_cast(float, u & 0xFFFF0000u);
}

// Half-wave gather-sum of one node's neighborhood from a [N][32]-uint bf16
// table. Returns (lo,hi) = full neighbor sums on ALL lanes (post shfl_xor).
__device__ __forceinline__ void gather_sum(const unsigned* __restrict__ G,
                                           const int* __restrict__ csr_src,
                                           int beg, int len, int h, int fl,
                                           float& lo_out, float& hi_out) {
    int cnt = (len - h + 1) >> 1;
    const int* ep = csr_src + beg + h;

    float lo0 = 0.f, lo1 = 0.f, lo2 = 0.f, lo3 = 0.f;
    float hi0 = 0.f, hi1 = 0.f, hi2 = 0.f, hi3 = 0.f;

    int k = 0;
    for (; k + 8 <= cnt; k += 8) {
        int s0 = ep[2 * k],      s1 = ep[2 * k + 2];
        int s2 = ep[2 * k + 4],  s3 = ep[2 * k + 6];
        int s4 = ep[2 * k + 8],  s5 = ep[2 * k + 10];
        int s6 = ep[2 * k + 12], s7 = ep[2 * k + 14];
        unsigned u0 = G[(size_t)s0 * 32 + fl];
        unsigned u1 = G[(size_t)s1 * 32 + fl];
        unsigned u2 = G[(size_t)s2 * 32 + fl];
        unsigned u3 = G[(size_t)s3 * 32 + fl];
        unsigned u4 = G[(size_t)s4 * 32 + fl];
        unsigned u5 = G[(size_t)s5 * 32 + fl];
        unsigned u6 = G[(size_t)s6 * 32 + fl];
        unsigned u7 = G[(size_t)s7 * 32 + fl];
        lo0 += bf_lo(u0) + bf_lo(u4);  hi0 += bf_hi(u0) + bf_hi(u4);
        lo1 += bf_lo(u1) + bf_lo(u5);  hi1 += bf_hi(u1) + bf_hi(u5);
        lo2 += bf_lo(u2) + bf_lo(u6);  hi2 += bf_hi(u2) + bf_hi(u6);
        lo3 += bf_lo(u3) + bf_lo(u7);  hi3 += bf_hi(u3) + bf_hi(u7);
    }
    for (; k + 4 <= cnt; k += 4) {
        int s0 = ep[2 * k],     s1 = ep[2 * k + 2];
        int s2 = ep[2 * k + 4], s3 = ep[2 * k + 6];
        unsigned u0 = G[(size_t)s0 * 32 + fl];
        unsigned u1 = G[(size_t)s1 * 32 + fl];
        unsigned u2 = G[(size_t)s2 * 32 + fl];
        unsigned u3 = G[(size_t)s3 * 32 + fl];
        lo0 += bf_lo(u0);  hi0 += bf_hi(u0);
        lo1 += bf_lo(u1);  hi1 += bf_hi(u1);
        lo2 += bf_lo(u2);  hi2 += bf_hi(u2);
        lo3 += bf_lo(u3);  hi3 += bf_hi(u3);
    }
    for (; k < cnt; ++k) {
        unsigned u = G[(size_t)ep[2 * k] * 32 + fl];
        lo1 += bf_lo(u);  hi1 += bf_hi(u);
    }

    float lo = (lo0 + lo1) + (lo2 + lo3);
    float hi = (hi0 + hi1) + (hi2 + hi3);
    lo += __shfl_xor(lo, 32);
    hi += __shfl_xor(hi, 32);
    lo_out = lo;  hi_out = hi;
}

// ---------------- GEMM, row-scale + bf16 epilogue (layer 1 only) -----------
template <int K, int DOUT>
__global__ __launch_bounds__(256) void gemm_scale(const float* __restrict__ A,
                                                  const float* __restrict__ W,
                                                  const float* __restrict__ dis,
                                                  ushort* __restrict__ G16, int N) {
    constexpr int CG   = DOUT / 4;
    constexpr int RG   = 256 / CG;
    constexpr int ROWS = RG * 4;
    constexpr int LDA  = K + 4;

    __shared__ __align__(16) float a_lds[ROWS * LDA];
    __shared__ __align__(16) float w_lds[K * DOUT];

    int t    = threadIdx.x;
    int row0 = blockIdx.x * ROWS;

    constexpr int WF4 = K * DOUT / 4;
    for (int q = t; q < WF4; q += 256)
        reinterpret_cast<float4*>(w_lds)[q] =
            reinterpret_cast<const float4*>(W)[q];

    constexpr int AF4 = ROWS * K / 4;
    for (int q = t; q < AF4; q += 256) {
        int r  = q / (K / 4);
        int kc = q % (K / 4);
        float4 v = make_float4(0.f, 0.f, 0.f, 0.f);
        int gr = row0 + r;
        if (gr < N)
            v = reinterpret_cast<const float4*>(A + (size_t)gr * K)[kc];
        *reinterpret_cast<float4*>(&a_lds[r * LDA + kc * 4]) = v;
    }
    __syncthreads();

    int c0 = (t % CG) * 4;
    int r0 = (t / CG) * 4;

    float4 acc[4] = {};
#pragma unroll 1
    for (int k = 0; k < K; k += 4) {
        float4 w0 = *reinterpret_cast<const float4*>(&w_lds[(k + 0) * DOUT + c0]);
        float4 w1 = *reinterpret_cast<const float4*>(&w_lds[(k + 1) * DOUT + c0]);
        float4 w2 = *reinterpret_cast<const float4*>(&w_lds[(k + 2) * DOUT + c0]);
        float4 w3 = *reinterpret_cast<const float4*>(&w_lds[(k + 3) * DOUT + c0]);
#pragma unroll
        for (int j = 0; j < 4; ++j) {
            float4 a4 = *reinterpret_cast<const float4*>(&a_lds[(r0 + j) * LDA + k]);
            acc[j].x += a4.x * w0.x + a4.y * w1.x + a4.z * w2.x + a4.w * w3.x;
            acc[j].y += a4.x * w0.y + a4.y * w1.y + a4.z * w2.y + a4.w * w3.y;
            acc[j].z += a4.x * w0.z + a4.y * w1.z + a4.z * w2.z + a4.w * w3.z;
            acc[j].w += a4.x * w0.w + a4.y * w1.w + a4.z * w2.w + a4.w * w3.w;
        }
    }

#pragma unroll
    for (int j = 0; j < 4; ++j) {
        int gr = row0 + r0 + j;
        if (gr < N) {
            float s = dis[gr];
            float4 o = acc[j];
            ushort4 pk;
            pk.x = r16(o.x * s); pk.y = r16(o.y * s);
            pk.z = r16(o.z * s); pk.w = r16(o.w * s);
            *reinterpret_cast<ushort4*>(&G16[(size_t)gr * DOUT + c0]) = pk;
        }
    }
}

// ---------------- Fused aggregate + next-layer GEMM (table out) -------------
// Per node n: v = relu(dis[n]*(G[n]+sum_src G[src]) + bias)  (current layer)
//             Gout[n] = bf16(dis[n] * (v @ Wn))              (next table)
// WRITE_F32: also emit v as fp32 [N][64] (the required z output).
// 8 nodes per wave; activation round-trips through per-wave LDS buffer;
// matvec (64 LDS reads + 64 FMA / col) hides in the gather stall cycles.
template <bool WRITE_F32>
__global__ __launch_bounds__(256) void agg_gemm_table(
    const unsigned* __restrict__ G,
    const int* __restrict__ row_ptr,
    const int* __restrict__ csr_src,
    const float* __restrict__ dis,
    const float* __restrict__ bias,
    const float* __restrict__ Wn,        // [64][64] fp32
    unsigned* __restrict__ Gout,
    float* __restrict__ Zout,
    int N) {
    __shared__ __align__(16) float w_lds[64 * 64];
    __shared__ __align__(16) float a_buf[4][64];

    int t = threadIdx.x;
    for (int q = t; q < 64 * 64 / 4; q += 256)
        reinterpret_cast<float4*>(w_lds)[q] =
            reinterpret_cast<const float4*>(Wn)[q];
    __syncthreads();

    int wave = t >> 6, lane = t & 63;
    int h = lane >> 5, fl = lane & 31;

    for (int j = 0; j < 8; ++j) {
        int n = (blockIdx.x * 4 + wave) * 8 + j;
        if (n >= N) break;   // wave-uniform

        int beg = row_ptr[n];
        int len = row_ptr[n + 1] - beg;
        float lo, hi;
        gather_sum(G, csr_src, beg, len, h, fl, lo, hi);

        float dn = dis[n];
        unsigned us = G[(size_t)n * 32 + fl];       // self-loop pair
        float2 b2 = reinterpret_cast<const float2*>(bias)[fl];
        float vlo = fmaxf(dn * (lo + bf_lo(us)) + b2.x, 0.f);
        float vhi = fmaxf(dn * (hi + bf_hi(us)) + b2.y, 0.f);

        if (h == 0) {
            *reinterpret_cast<float2*>(&a_buf[wave][2 * fl]) =
                make_float2(vlo, vhi);
            if (WRITE_F32)
                reinterpret_cast<float2*>(Zout)[(size_t)n * 32 + fl] =
                    make_float2(vlo, vhi);
        }
        __builtin_amdgcn_wave_barrier();   // a_buf write -> read (in-order DS)

        // matvec: this lane owns output column `lane`
        float y0 = 0.f, y1 = 0.f, y2 = 0.f, y3 = 0.f;
        for (int k = 0; k < 64; k += 4) {
            float4 a4 = *reinterpret_cast<const float4*>(&a_buf[wave][k]);
            y0 += a4.x * w_lds[(k + 0) * 64 + lane];
            y1 += a4.y * w_lds[(k + 1) * 64 + lane];
            y2 += a4.z * w_lds[(k + 2) * 64 + lane];
            y3 += a4.w * w_lds[(k + 3) * 64 + lane];
        }
        float y = (y0 + y1) + (y2 + y3);
        __builtin_amdgcn_wave_barrier();   // reads done before next j's write

        float ylo = __shfl(y, 2 * fl);
        float yhi = __shfl(y, 2 * fl + 1);
        if (h == 0) {
            unsigned pk = (unsigned)r16(dn * ylo) | ((unsigned)r16(dn * yhi) << 16);
            Gout[(size_t)n * 32 + fl] = pk;
        }
    }
}

// ---------------- Fused aggregate + final GEMM (x_hat out) ------------------
// t = dis[n]*(s3[n]+sum s3[src]);  x_hat[n] = t @ W4 + b4  (64->128, fp32 out)
// W4 held as bf16 pairs in LDS (16 KB) to keep 8 blocks/CU occupancy.
__global__ __launch_bounds__(256) void agg_gemm_out(
    const unsigned* __restrict__ G,      // s3 table
    const int* __restrict__ row_ptr,
    const int* __restrict__ csr_src,
    const float* __restrict__ dis,
    const float* __restrict__ W4,        // [64][128] fp32
    const float* __restrict__ b4,        // [128]
    float* __restrict__ Xhat,            // [N][128]
    int N) {
    __shared__ unsigned w_lds[64 * 64];  // w_lds[k*64+p] = bf16(W4[k][2p], W4[k][2p+1])
    __shared__ __align__(16) float a_buf[4][64];

    int t = threadIdx.x;
    for (int q = t; q < 4096; q += 256) {
        float2 wv = reinterpret_cast<const float2*>(W4)[q];
        w_lds[q] = (unsigned)r16(wv.x) | ((unsigned)r16(wv.y) << 16);
    }
    __syncthreads();

    int wave = t >> 6, lane = t & 63;
    int h = lane >> 5, fl = lane & 31;

    for (int j = 0; j < 8; ++j) {
        int n = (blockIdx.x * 4 + wave) * 8 + j;
        if (n >= N) break;

        int beg = row_ptr[n];
        int len = row_ptr[n + 1] - beg;
        float lo, hi;
        gather_sum(G, csr_src, beg, len, h, fl, lo, hi);

        float dn = dis[n];
        unsigned us = G[(size_t)n * 32 + fl];
        float vlo = dn * (lo + bf_lo(us));   // t features 2fl, 2fl+1
        float vhi = dn * (hi + bf_hi(us));

        if (h == 0)
            *reinterpret_cast<float2*>(&a_buf[wave][2 * fl]) =
                make_float2(vlo, vhi);
        __builtin_amdgcn_wave_barrier();

        // this lane owns output columns (2*lane, 2*lane+1)
        float y0 = 0.f, y1 = 0.f, y2 = 0.f, y3 = 0.f;
        for (int k = 0; k < 64; k += 2) {
            float2 a2 = *reinterpret_cast<const float2*>(&a_buf[wave][k]);
            unsigned w0 = w_lds[(k + 0) * 64 + lane];
            unsigned w1 = w_lds[(k + 1) * 64 + lane];
            y0 += a2.x * bf_lo(w0);  y1 += a2.x * bf_hi(w0);
            y2 += a2.y * bf_lo(w1);  y3 += a2.y * bf_hi(w1);
        }
        __builtin_amdgcn_wave_barrier();

        float2 bb = reinterpret_cast<const float2*>(b4)[lane];
        reinterpret_cast<float2*>(Xhat)[(size_t)n * 64 + lane] =
            make_float2(y0 + y2 + bb.x, y1 + y3 + bb.y);
    }
}

// ---------------- Plain aggregation (layer 3 -> s3 table) -------------------
__global__ __launch_bounds__(256) void aggregate_s3(const unsigned* __restrict__ G,
                                                    const int* __restrict__ row_ptr,
                                                    const int* __restrict__ csr_src,
                                                    const float* __restrict__ dis,
                                                    const float* __restrict__ bias,
                                                    unsigned* __restrict__ Out, int N) {
    int wave = threadIdx.x >> 6;
    int lane = threadIdx.x & 63;
    int n = blockIdx.x * 4 + wave;
    if (n >= N) return;
    int h = lane >> 5, fl = lane & 31;

    int beg = row_ptr[n];
    int len = row_ptr[n + 1] - beg;
    float lo, hi;
    gather_sum(G, csr_src, beg, len, h, fl, lo, hi);

    if (h == 0) {
        unsigned us = G[(size_t)n * 32 + fl];
        float dn = dis[n];
        float2 b2 = reinterpret_cast<const float2*>(bias)[fl];
        float vlo = fmaxf(dn * (lo + bf_lo(us)) + b2.x, 0.f);
        float vhi = fmaxf(dn * (hi + bf_hi(us)) + b2.y, 0.f);
        // s3 = bf16(dis[n] * v) — extra dn for the reassociated layer 4
        unsigned pk = (unsigned)r16(dn * vlo) | ((unsigned)r16(dn * vhi) << 16);
        Out[(size_t)n * 32 + fl] = pk;
    }
}

// ---------------- Launch ----------------

extern "C" void kernel_launch(void* const* d_in, const int* in_sizes, int n_in,
                              void* d_out, int out_size, void* d_ws, size_t ws_size,
                              hipStream_t stream) {
    const float* x     = (const float*)d_in[0];
    const int*   edges = (const int*)d_in[1];   // [2, E] row-major
    const float* W1 = (const float*)d_in[2];
    const float* b1 = (const float*)d_in[3];
    const float* W2 = (const float*)d_in[4];
    const float* b2 = (const float*)d_in[5];
    const float* W3 = (const float*)d_in[6];
    const float* b3 = (const float*)d_in[7];
    const float* W4 = (const float*)d_in[8];
    const float* b4 = (const float*)d_in[9];

    const int DIN = 128, DH = 64;
    int N = in_sizes[0] / DIN;
    int E = in_sizes[1] / 2;

    const int* e_src = edges;
    const int* e_dst = edges + E;

    float* out   = (float*)d_out;
    float* x_hat = out;                       // [N,128]
    float* z     = out + (size_t)N * DIN;     // [N,64]

    int B    = (N + 2047) / 2048;
    int Npad = B * 2048;

    char*  ws  = (char*)d_ws;
    size_t woff = 0;
    auto carve = [&](size_t bytes) {
        void* p = ws + woff;
        woff = (woff + bytes + 255) & ~(size_t)255;
        return p;
    };
    float*    dis        = (float*)   carve((size_t)N * 4);
    int*      deg        = (int*)     carve((size_t)Npad * 4);
    int*      row_ptr    = (int*)     carve((size_t)(N + 1) * 4);
    int*      csr_src    = (int*)     carve((size_t)E * 4);
    int*      block_sums = (int*)     carve((size_t)B * 4);
    int*      block_off  = (int*)     carve((size_t)B * 4);
    unsigned* gA         = (unsigned*)carve((size_t)N * DH * 2);  // ping
    unsigned* gB         = (unsigned*)carve((size_t)N * DH * 2);  // pong
    (void)ws_size;

    int nb_e   = (E + 255) / 256;
    int nb_agg = (N + 3) / 4;
    int nb_f   = (N + 31) / 32;    // fused: 4 waves x 8 nodes per block

    // CSR build
    init_k<<<(Npad + 255) / 256, 256, 0, stream>>>(deg, Npad);
    hist_deg<<<nb_e, 256, 0, stream>>>(e_dst, deg, E);
    scan_phase1<<<B, 256, 0, stream>>>(deg, block_sums);
    scan_phase2<<<1, 256, 0, stream>>>(block_sums, block_off, row_ptr, B, N);
    scan_phase3<<<B, 256, 0, stream>>>(deg, block_off, row_ptr, dis, N);
    fill_csr<<<nb_e, 256, 0, stream>>>(e_src, e_dst, row_ptr, deg, csr_src, E);

    // Layer 1 GEMM: g1 = bf16(dis*(x @ W1)) -> gA
    gemm_scale<128, 64><<<(N + 63) / 64, 256, 0, stream>>>(
        x, W1, dis, (ushort*)gA, N);

    // Fused layer 1->2: h = relu(agg(gA)+b1); g2 = bf16(dis*(h@W2)) -> gB
    agg_gemm_table<false><<<nb_f, 256, 0, stream>>>(
        gA, row_ptr, csr_src, dis, b1, W2, gB, nullptr, N);

    // Fused layer 2->3: z = relu(agg(gB)+b2) -> d_out; g3 = bf16(dis*(z@W3)) -> gA
    agg_gemm_table<true><<<nb_f, 256, 0, stream>>>(
        gB, row_ptr, csr_src, dis, b2, W3, gA, z, N);

    // Layer 3: s3 = bf16(dis * relu(agg(gA)+b3)) -> gB
    aggregate_s3<<<nb_agg, 256, 0, stream>>>(
        gA, row_ptr, csr_src, dis, b3, gB, N);

    // Fused layer 4: t = dis*agg(gB); x_hat = t @ W4 + b4
    agg_gemm_out<<<nb_f, 256, 0, stream>>>(
        gB, row_ptr, csr_src, dis, W4, b4, x_hat, N);
}

// Round 11
// 325.355 us; speedup vs baseline: 1.0467x; 1.0467x over previous
//
#include <hip/hip_runtime.h>
#include <hip/hip_bf16.h>

// DOMINANT GCN autoencoder on MI355X.
// R11: keep agg+GEMM fusion ONLY for the 64->64 mid layers (R10 showed they
// saved ~20us), with nodes-per-wave 8->2 for gather latency-hiding (25k waves).
// Layer 4 unfused again (R10's fused version serialized gather->matvec and cut
// wave count 8x: 62us vs 37us unfused). CSR + layer-1 GEMM as R9.

// ---------------- CSR build ----------------

__global__ __launch_bounds__(256) void init_k(int* __restrict__ deg, int Npad) {
    int i = blockIdx.x * 256 + threadIdx.x;
    if (i < Npad) deg[i] = 0;
}

__global__ __launch_bounds__(256) void hist_deg(const int* __restrict__ dst,
                                                int* __restrict__ deg, int E) {
    int e = blockIdx.x * 256 + threadIdx.x;
    if (e < E) atomicAdd(&deg[dst[e]], 1);
}

__global__ __launch_bounds__(256) void scan_phase1(const int* __restrict__ deg,
                                                   int* __restrict__ block_sums) {
    int b = blockIdx.x, t = threadIdx.x;
    const int4* p = reinterpret_cast<const int4*>(deg + (size_t)b * 2048);
    int4 a = p[t * 2], c = p[t * 2 + 1];
    int s = a.x + a.y + a.z + a.w + c.x + c.y + c.z + c.w;
#pragma unroll
    for (int off = 32; off; off >>= 1) s += __shfl_down(s, off);
    __shared__ int wsum[4];
    if ((t & 63) == 0) wsum[t >> 6] = s;
    __syncthreads();
    if (t == 0) block_sums[b] = wsum[0] + wsum[1] + wsum[2] + wsum[3];
}

__global__ __launch_bounds__(256) void scan_phase2(const int* __restrict__ block_sums,
                                                   int* __restrict__ block_off,
                                                   int* __restrict__ row_ptr,
                                                   int B, int N) {
    __shared__ int s[256];
    int t = threadIdx.x;
    int v = (t < B) ? block_sums[t] : 0;
    s[t] = v;
    __syncthreads();
#pragma unroll
    for (int off = 1; off < 256; off <<= 1) {
        int u = (t >= off) ? s[t - off] : 0;
        __syncthreads();
        s[t] += u;
        __syncthreads();
    }
    if (t < B) block_off[t] = s[t] - v;
    if (t == 255) row_ptr[N] = s[255];
}

__global__ __launch_bounds__(256) void scan_phase3(const int* __restrict__ deg,
                                                   const int* __restrict__ block_off,
                                                   int* __restrict__ row_ptr,
                                                   float* __restrict__ dis, int N) {
    int b = blockIdx.x, t = threadIdx.x;
    int base = b * 2048 + t * 8;
    const int4* p = reinterpret_cast<const int4*>(deg + base);
    int4 a = p[0], c = p[1];
    int d[8] = {a.x, a.y, a.z, a.w, c.x, c.y, c.z, c.w};
    int pre[8], s = 0;
#pragma unroll
    for (int j = 0; j < 8; ++j) { pre[j] = s; s += d[j]; }
    __shared__ int ls[256];
    ls[t] = s;
    __syncthreads();
#pragma unroll
    for (int off = 1; off < 256; off <<= 1) {
        int u = (t >= off) ? ls[t - off] : 0;
        __syncthreads();
        ls[t] += u;
        __syncthreads();
    }
    int excl = ls[t] - s + block_off[b];
#pragma unroll
    for (int j = 0; j < 8; ++j) {
        int i = base + j;
        if (i < N) {
            row_ptr[i] = excl + pre[j];
            dis[i] = rsqrtf((float)(d[j] + 1));
        }
    }
}

__global__ __launch_bounds__(256) void fill_csr(const int* __restrict__ src,
                                                const int* __restrict__ dst,
                                                const int* __restrict__ row_ptr,
                                                int* __restrict__ deg,
                                                int* __restrict__ csr_src, int E) {
    int e = blockIdx.x * 256 + threadIdx.x;
    if (e < E) {
        int d = dst[e];
        int old = atomicSub(&deg[d], 1);
        csr_src[row_ptr[d] + old - 1] = src[e];
    }
}

// ---------------- helpers ----------------

__device__ __forceinline__ ushort r16(float f) {
    __hip_bfloat16 h = __float2bfloat16(f);   // round-to-nearest-even
    return *reinterpret_cast<ushort*>(&h);
}
__device__ __forceinline__ float bf_lo(unsigned u) {
    return __builtin_bit_cast(float, u << 16);
}
__device__ __forceinline__ float bf_hi(unsigned u) {
    return __builtin_bit_cast(float, u & 0xFFFF0000u);
}

// Half-wave gather-sum from a [N][32]-uint bf16 table.
// Returns full neighbor sums on ALL lanes (post shfl_xor).
__device__ __forceinline__ void gather_sum(const unsigned* __restrict__ G,
                                           const int* __restrict__ csr_src,
                                           int beg, int len, int h, int fl,
                                           float& lo_out, float& hi_out) {
    int cnt = (len - h + 1) >> 1;
    const int* ep = csr_src + beg + h;

    float lo0 = 0.f, lo1 = 0.f, lo2 = 0.f, lo3 = 0.f;
    float hi0 = 0.f, hi1 = 0.f, hi2 = 0.f, hi3 = 0.f;

    int k = 0;
    for (; k + 8 <= cnt; k += 8) {
        int s0 = ep[2 * k],      s1 = ep[2 * k + 2];
        int s2 = ep[2 * k + 4],  s3 = ep[2 * k + 6];
        int s4 = ep[2 * k + 8],  s5 = ep[2 * k + 10];
        int s6 = ep[2 * k + 12], s7 = ep[2 * k + 14];
        unsigned u0 = G[(size_t)s0 * 32 + fl];
        unsigned u1 = G[(size_t)s1 * 32 + fl];
        unsigned u2 = G[(size_t)s2 * 32 + fl];
        unsigned u3 = G[(size_t)s3 * 32 + fl];
        unsigned u4 = G[(size_t)s4 * 32 + fl];
        unsigned u5 = G[(size_t)s5 * 32 + fl];
        unsigned u6 = G[(size_t)s6 * 32 + fl];
        unsigned u7 = G[(size_t)s7 * 32 + fl];
        lo0 += bf_lo(u0) + bf_lo(u4);  hi0 += bf_hi(u0) + bf_hi(u4);
        lo1 += bf_lo(u1) + bf_lo(u5);  hi1 += bf_hi(u1) + bf_hi(u5);
        lo2 += bf_lo(u2) + bf_lo(u6);  hi2 += bf_hi(u2) + bf_hi(u6);
        lo3 += bf_lo(u3) + bf_lo(u7);  hi3 += bf_hi(u3) + bf_hi(u7);
    }
    for (; k + 4 <= cnt; k += 4) {
        int s0 = ep[2 * k],     s1 = ep[2 * k + 2];
        int s2 = ep[2 * k + 4], s3 = ep[2 * k + 6];
        unsigned u0 = G[(size_t)s0 * 32 + fl];
        unsigned u1 = G[(size_t)s1 * 32 + fl];
        unsigned u2 = G[(size_t)s2 * 32 + fl];
        unsigned u3 = G[(size_t)s3 * 32 + fl];
        lo0 += bf_lo(u0);  hi0 += bf_hi(u0);
        lo1 += bf_lo(u1);  hi1 += bf_hi(u1);
        lo2 += bf_lo(u2);  hi2 += bf_hi(u2);
        lo3 += bf_lo(u3);  hi3 += bf_hi(u3);
    }
    for (; k < cnt; ++k) {
        unsigned u = G[(size_t)ep[2 * k] * 32 + fl];
        lo1 += bf_lo(u);  hi1 += bf_hi(u);
    }

    float lo = (lo0 + lo1) + (lo2 + lo3);
    float hi = (hi0 + hi1) + (hi2 + hi3);
    lo += __shfl_xor(lo, 32);
    hi += __shfl_xor(hi, 32);
    lo_out = lo;  hi_out = hi;
}

// ---------------- GEMM, row-scale + bf16 epilogue (layer 1) ----------------
template <int K, int DOUT>
__global__ __launch_bounds__(256) void gemm_scale(const float* __restrict__ A,
                                                  const float* __restrict__ W,
                                                  const float* __restrict__ dis,
                                                  ushort* __restrict__ G16, int N) {
    constexpr int CG   = DOUT / 4;
    constexpr int RG   = 256 / CG;
    constexpr int ROWS = RG * 4;
    constexpr int LDA  = K + 4;

    __shared__ __align__(16) float a_lds[ROWS * LDA];
    __shared__ __align__(16) float w_lds[K * DOUT];

    int t    = threadIdx.x;
    int row0 = blockIdx.x * ROWS;

    constexpr int WF4 = K * DOUT / 4;
    for (int q = t; q < WF4; q += 256)
        reinterpret_cast<float4*>(w_lds)[q] =
            reinterpret_cast<const float4*>(W)[q];

    constexpr int AF4 = ROWS * K / 4;
    for (int q = t; q < AF4; q += 256) {
        int r  = q / (K / 4);
        int kc = q % (K / 4);
        float4 v = make_float4(0.f, 0.f, 0.f, 0.f);
        int gr = row0 + r;
        if (gr < N)
            v = reinterpret_cast<const float4*>(A + (size_t)gr * K)[kc];
        *reinterpret_cast<float4*>(&a_lds[r * LDA + kc * 4]) = v;
    }
    __syncthreads();

    int c0 = (t % CG) * 4;
    int r0 = (t / CG) * 4;

    float4 acc[4] = {};
#pragma unroll 1
    for (int k = 0; k < K; k += 4) {
        float4 w0 = *reinterpret_cast<const float4*>(&w_lds[(k + 0) * DOUT + c0]);
        float4 w1 = *reinterpret_cast<const float4*>(&w_lds[(k + 1) * DOUT + c0]);
        float4 w2 = *reinterpret_cast<const float4*>(&w_lds[(k + 2) * DOUT + c0]);
        float4 w3 = *reinterpret_cast<const float4*>(&w_lds[(k + 3) * DOUT + c0]);
#pragma unroll
        for (int j = 0; j < 4; ++j) {
            float4 a4 = *reinterpret_cast<const float4*>(&a_lds[(r0 + j) * LDA + k]);
            acc[j].x += a4.x * w0.x + a4.y * w1.x + a4.z * w2.x + a4.w * w3.x;
            acc[j].y += a4.x * w0.y + a4.y * w1.y + a4.z * w2.y + a4.w * w3.y;
            acc[j].z += a4.x * w0.z + a4.y * w1.z + a4.z * w2.z + a4.w * w3.z;
            acc[j].w += a4.x * w0.w + a4.y * w1.w + a4.z * w2.w + a4.w * w3.w;
        }
    }

#pragma unroll
    for (int j = 0; j < 4; ++j) {
        int gr = row0 + r0 + j;
        if (gr < N) {
            float s = dis[gr];
            float4 o = acc[j];
            ushort4 pk;
            pk.x = r16(o.x * s); pk.y = r16(o.y * s);
            pk.z = r16(o.z * s); pk.w = r16(o.w * s);
            *reinterpret_cast<ushort4*>(&G16[(size_t)gr * DOUT + c0]) = pk;
        }
    }
}

// ---------------- GEMM, bias epilogue, fp32 out (final layer) ----------------
template <int K, int DOUT>
__global__ __launch_bounds__(256) void gemm_bias(const float* __restrict__ A,
                                                 const float* __restrict__ W,
                                                 const float* __restrict__ bias,
                                                 float* __restrict__ Out, int N) {
    constexpr int CG   = DOUT / 4;
    constexpr int RG   = 256 / CG;
    constexpr int ROWS = RG * 4;
    constexpr int LDA  = K + 4;

    __shared__ __align__(16) float a_lds[ROWS * LDA];
    __shared__ __align__(16) float w_lds[K * DOUT];

    int t    = threadIdx.x;
    int row0 = blockIdx.x * ROWS;

    constexpr int WF4 = K * DOUT / 4;
    for (int q = t; q < WF4; q += 256)
        reinterpret_cast<float4*>(w_lds)[q] =
            reinterpret_cast<const float4*>(W)[q];

    constexpr int AF4 = ROWS * K / 4;
    for (int q = t; q < AF4; q += 256) {
        int r  = q / (K / 4);
        int kc = q % (K / 4);
        float4 v = make_float4(0.f, 0.f, 0.f, 0.f);
        int gr = row0 + r;
        if (gr < N)
            v = reinterpret_cast<const float4*>(A + (size_t)gr * K)[kc];
        *reinterpret_cast<float4*>(&a_lds[r * LDA + kc * 4]) = v;
    }
    __syncthreads();

    int c0 = (t % CG) * 4;
    int r0 = (t / CG) * 4;

    float4 acc[4] = {};
#pragma unroll 1
    for (int k = 0; k < K; k += 4) {
        float4 w0 = *reinterpret_cast<const float4*>(&w_lds[(k + 0) * DOUT + c0]);
        float4 w1 = *reinterpret_cast<const float4*>(&w_lds[(k + 1) * DOUT + c0]);
        float4 w2 = *reinterpret_cast<const float4*>(&w_lds[(k + 2) * DOUT + c0]);
        float4 w3 = *reinterpret_cast<const float4*>(&w_lds[(k + 3) * DOUT + c0]);
#pragma unroll
        for (int j = 0; j < 4; ++j) {
            float4 a4 = *reinterpret_cast<const float4*>(&a_lds[(r0 + j) * LDA + k]);
            acc[j].x += a4.x * w0.x + a4.y * w1.x + a4.z * w2.x + a4.w * w3.x;
            acc[j].y += a4.x * w0.y + a4.y * w1.y + a4.z * w2.y + a4.w * w3.y;
            acc[j].z += a4.x * w0.z + a4.y * w1.z + a4.z * w2.z + a4.w * w3.z;
            acc[j].w += a4.x * w0.w + a4.y * w1.w + a4.z * w2.w + a4.w * w3.w;
        }
    }

    float4 b4v = *reinterpret_cast<const float4*>(&bias[c0]);
#pragma unroll
    for (int j = 0; j < 4; ++j) {
        int gr = row0 + r0 + j;
        if (gr < N) {
            float4 o = acc[j];
            o.x += b4v.x; o.y += b4v.y; o.z += b4v.z; o.w += b4v.w;
            reinterpret_cast<float4*>(Out + (size_t)gr * DOUT)[c0 / 4] = o;
        }
    }
}

// ---------------- Fused aggregate + next-layer 64->64 GEMM ------------------
// 2 nodes per wave (latency-hiding via wave count; R10's 8/wave starved it).
// v = relu(dis[n]*(G[n]+sum)+bias); Gout[n] = bf16(dis[n]*(v@Wn)).
// WRITE_F32: also emit v as fp32 (the z output).
template <bool WRITE_F32>
__global__ __launch_bounds__(256) void agg_gemm_table(
    const unsigned* __restrict__ G,
    const int* __restrict__ row_ptr,
    const int* __restrict__ csr_src,
    const float* __restrict__ dis,
    const float* __restrict__ bias,
    const float* __restrict__ Wn,        // [64][64] fp32
    unsigned* __restrict__ Gout,
    float* __restrict__ Zout,
    int N) {
    __shared__ __align__(16) float w_lds[64 * 64];
    __shared__ __align__(16) float a_buf[4][64];

    int t = threadIdx.x;
    for (int q = t; q < 64 * 64 / 4; q += 256)
        reinterpret_cast<float4*>(w_lds)[q] =
            reinterpret_cast<const float4*>(Wn)[q];
    __syncthreads();

    int wave = t >> 6, lane = t & 63;
    int h = lane >> 5, fl = lane & 31;

    for (int j = 0; j < 2; ++j) {
        int n = (blockIdx.x * 4 + wave) * 2 + j;
        if (n >= N) break;   // wave-uniform

        int beg = row_ptr[n];
        int len = row_ptr[n + 1] - beg;
        float lo, hi;
        gather_sum(G, csr_src, beg, len, h, fl, lo, hi);

        float dn = dis[n];
        unsigned us = G[(size_t)n * 32 + fl];       // self-loop pair
        float2 b2 = reinterpret_cast<const float2*>(bias)[fl];
        float vlo = fmaxf(dn * (lo + bf_lo(us)) + b2.x, 0.f);
        float vhi = fmaxf(dn * (hi + bf_hi(us)) + b2.y, 0.f);

        if (h == 0) {
            *reinterpret_cast<float2*>(&a_buf[wave][2 * fl]) =
                make_float2(vlo, vhi);
            if (WRITE_F32)
                reinterpret_cast<float2*>(Zout)[(size_t)n * 32 + fl] =
                    make_float2(vlo, vhi);
        }
        __builtin_amdgcn_wave_barrier();   // a_buf write -> read (in-order DS)

        // matvec: this lane owns output column `lane`
        float y0 = 0.f, y1 = 0.f, y2 = 0.f, y3 = 0.f;
        for (int k = 0; k < 64; k += 4) {
            float4 a4 = *reinterpret_cast<const float4*>(&a_buf[wave][k]);
            y0 += a4.x * w_lds[(k + 0) * 64 + lane];
            y1 += a4.y * w_lds[(k + 1) * 64 + lane];
            y2 += a4.z * w_lds[(k + 2) * 64 + lane];
            y3 += a4.w * w_lds[(k + 3) * 64 + lane];
        }
        float y = (y0 + y1) + (y2 + y3);
        __builtin_amdgcn_wave_barrier();   // reads done before next j's write

        float ylo = __shfl(y, 2 * fl);
        float yhi = __shfl(y, 2 * fl + 1);
        if (h == 0) {
            unsigned pk = (unsigned)r16(dn * ylo) | ((unsigned)r16(dn * yhi) << 16);
            Gout[(size_t)n * 32 + fl] = pk;
        }
    }
}

// ---------------- Plain aggregations ----------------------------------------
// Layer 3: s3 = bf16(dis * relu(agg + b3)) table.
__global__ __launch_bounds__(256) void aggregate_s3(const unsigned* __restrict__ G,
                                                    const int* __restrict__ row_ptr,
                                                    const int* __restrict__ csr_src,
                                                    const float* __restrict__ dis,
                                                    const float* __restrict__ bias,
                                                    unsigned* __restrict__ Out, int N) {
    int wave = threadIdx.x >> 6;
    int lane = threadIdx.x & 63;
    int n = blockIdx.x * 4 + wave;
    if (n >= N) return;
    int h = lane >> 5, fl = lane & 31;

    int beg = row_ptr[n];
    int len = row_ptr[n + 1] - beg;
    float lo, hi;
    gather_sum(G, csr_src, beg, len, h, fl, lo, hi);

    if (h == 0) {
        unsigned us = G[(size_t)n * 32 + fl];
        float dn = dis[n];
        float2 b2 = reinterpret_cast<const float2*>(bias)[fl];
        float vlo = fmaxf(dn * (lo + bf_lo(us)) + b2.x, 0.f);
        float vhi = fmaxf(dn * (hi + bf_hi(us)) + b2.y, 0.f);
        // s3 = bf16(dis[n] * v) — extra dn for the reassociated layer 4
        unsigned pk = (unsigned)r16(dn * vlo) | ((unsigned)r16(dn * vhi) << 16);
        Out[(size_t)n * 32 + fl] = pk;
    }
}

// Layer 4 aggregate: t = dis[n]*(s3[n]+sum s3[src]) (fp32, no bias/relu).
__global__ __launch_bounds__(256) void aggregate_t(const unsigned* __restrict__ G,
                                                   const int* __restrict__ row_ptr,
                                                   const int* __restrict__ csr_src,
                                                   const float* __restrict__ dis,
                                                   float* __restrict__ Out, int N) {
    int wave = threadIdx.x >> 6;
    int lane = threadIdx.x & 63;
    int n = blockIdx.x * 4 + wave;
    if (n >= N) return;
    int h = lane >> 5, fl = lane & 31;

    int beg = row_ptr[n];
    int len = row_ptr[n + 1] - beg;
    float lo, hi;
    gather_sum(G, csr_src, beg, len, h, fl, lo, hi);

    if (h == 0) {
        unsigned us = G[(size_t)n * 32 + fl];
        float dn = dis[n];
        reinterpret_cast<float2*>(Out)[(size_t)n * 32 + fl] =
            make_float2(dn * (lo + bf_lo(us)), dn * (hi + bf_hi(us)));
    }
}

// ---------------- Launch ----------------

extern "C" void kernel_launch(void* const* d_in, const int* in_sizes, int n_in,
                              void* d_out, int out_size, void* d_ws, size_t ws_size,
                              hipStream_t stream) {
    const float* x     = (const float*)d_in[0];
    const int*   edges = (const int*)d_in[1];   // [2, E] row-major
    const float* W1 = (const float*)d_in[2];
    const float* b1 = (const float*)d_in[3];
    const float* W2 = (const float*)d_in[4];
    const float* b2 = (const float*)d_in[5];
    const float* W3 = (const float*)d_in[6];
    const float* b3 = (const float*)d_in[7];
    const float* W4 = (const float*)d_in[8];
    const float* b4 = (const float*)d_in[9];

    const int DIN = 128, DH = 64;
    int N = in_sizes[0] / DIN;
    int E = in_sizes[1] / 2;

    const int* e_src = edges;
    const int* e_dst = edges + E;

    float* out   = (float*)d_out;
    float* x_hat = out;                       // [N,128]
    float* z     = out + (size_t)N * DIN;     // [N,64]

    int B    = (N + 2047) / 2048;
    int Npad = B * 2048;

    char*  ws  = (char*)d_ws;
    size_t woff = 0;
    auto carve = [&](size_t bytes) {
        void* p = ws + woff;
        woff = (woff + bytes + 255) & ~(size_t)255;
        return p;
    };
    float*    dis        = (float*)   carve((size_t)N * 4);
    int*      deg        = (int*)     carve((size_t)Npad * 4);
    int*      row_ptr    = (int*)     carve((size_t)(N + 1) * 4);
    int*      csr_src    = (int*)     carve((size_t)E * 4);
    int*      block_sums = (int*)     carve((size_t)B * 4);
    int*      block_off  = (int*)     carve((size_t)B * 4);
    unsigned* gA         = (unsigned*)carve((size_t)N * DH * 2);  // ping
    unsigned* gB         = (unsigned*)carve((size_t)N * DH * 2);  // pong
    float*    t          = (float*)   carve((size_t)N * DH * 4);  // layer-4 agg
    (void)ws_size;

    int nb_e   = (E + 255) / 256;
    int nb_agg = (N + 3) / 4;
    int nb_f   = (N + 7) / 8;      // fused: 4 waves x 2 nodes per block

    // CSR build
    init_k<<<(Npad + 255) / 256, 256, 0, stream>>>(deg, Npad);
    hist_deg<<<nb_e, 256, 0, stream>>>(e_dst, deg, E);
    scan_phase1<<<B, 256, 0, stream>>>(deg, block_sums);
    scan_phase2<<<1, 256, 0, stream>>>(block_sums, block_off, row_ptr, B, N);
    scan_phase3<<<B, 256, 0, stream>>>(deg, block_off, row_ptr, dis, N);
    fill_csr<<<nb_e, 256, 0, stream>>>(e_src, e_dst, row_ptr, deg, csr_src, E);

    // Layer 1 GEMM: g1 = bf16(dis*(x @ W1)) -> gA
    gemm_scale<128, 64><<<(N + 63) / 64, 256, 0, stream>>>(
        x, W1, dis, (ushort*)gA, N);

    // Fused 1->2: h = relu(agg(gA)+b1); gB = bf16(dis*(h@W2))
    agg_gemm_table<false><<<nb_f, 256, 0, stream>>>(
        gA, row_ptr, csr_src, dis, b1, W2, gB, nullptr, N);

    // Fused 2->3: z = relu(agg(gB)+b2) -> d_out; gA = bf16(dis*(z@W3))
    agg_gemm_table<true><<<nb_f, 256, 0, stream>>>(
        gB, row_ptr, csr_src, dis, b2, W3, gA, z, N);

    // Layer 3: s3 = bf16(dis * relu(agg(gA)+b3)) -> gB
    aggregate_s3<<<nb_agg, 256, 0, stream>>>(
        gA, row_ptr, csr_src, dis, b3, gB, N);

    // Layer 4 (unfused): t = dis*agg(gB); x_hat = t @ W4 + b4
    aggregate_t<<<nb_agg, 256, 0, stream>>>(
        gB, row_ptr, csr_src, dis, t, N);
    gemm_bias<64, 128><<<(N + 31) / 32, 256, 0, stream>>>(t, W4, b4, x_hat, N);
}